// Round 1
// baseline (299.533 us; speedup 1.0000x reference)
//
#include <hip/hip_runtime.h>
#include <math.h>

#define NB 4
#define SEQ 1024
#define DIM 512
#define NH 8
#define HDIM 64
#define HALFW 16
#define KTOP 716
#define THRESH 0.05f
#define PATT 0.3f
#define SCALE 0.125f

// ---------------- selector: partial pooling ----------------
__global__ __launch_bounds__(256) void partial_pool_kernel(
    const float* __restrict__ x, float* __restrict__ partial) {
  int bid = blockIdx.x;          // NB*32
  int b = bid >> 5, c = bid & 31;
  int t = threadIdx.x;
  const float* xb = x + ((size_t)b * SEQ + (size_t)c * 32) * DIM;
  for (int d = t; d < DIM; d += 256) {
    float acc = 0.f;
#pragma unroll 8
    for (int l = 0; l < 32; ++l) acc += xb[(size_t)l * DIM + d];
    partial[(size_t)bid * DIM + d] = acc;
  }
}

// ---------------- selector: MLP + flags ----------------
__global__ __launch_bounds__(256) void selector_mlp_kernel(
    const float* __restrict__ partial,
    const float* __restrict__ w1, const float* __restrict__ b1,
    const float* __restrict__ w2, const float* __restrict__ b2,
    const float* __restrict__ w3, const float* __restrict__ b3,
    const float* __restrict__ pbias, float* __restrict__ flags) {
  int b = blockIdx.x;
  int t = threadIdx.x;
  __shared__ float pooled[DIM];
  __shared__ float h1[DIM];
  __shared__ float h2[DIM / 2];
  __shared__ float lg[3];
  for (int d = t; d < DIM; d += 256) {
    float acc = 0.f;
    for (int c = 0; c < 32; ++c) acc += partial[(size_t)(b * 32 + c) * DIM + d];
    pooled[d] = acc * (1.0f / SEQ);
  }
  __syncthreads();
  for (int i = t; i < DIM; i += 256) {
    float acc = b1[i];
    const float* w = w1 + (size_t)i * DIM;
    for (int k = 0; k < DIM; ++k) acc = fmaf(pooled[k], w[k], acc);
    h1[i] = fmaxf(acc, 0.f);
  }
  __syncthreads();
  for (int i = t; i < DIM / 2; i += 256) {
    float acc = b2[i];
    const float* w = w2 + (size_t)i * DIM;
    for (int k = 0; k < DIM; ++k) acc = fmaf(h1[k], w[k], acc);
    h2[i] = fmaxf(acc, 0.f);
  }
  __syncthreads();
  if (t < 3) {
    float acc = b3[t] + pbias[t];
    const float* w = w3 + t * (DIM / 2);
    for (int k = 0; k < DIM / 2; ++k) acc = fmaf(h2[k], w[k], acc);
    lg[t] = acc * (1.0f / PATT);
  }
  __syncthreads();
  if (t == 0) {
    float m = fmaxf(lg[0], fmaxf(lg[1], lg[2]));
    float e0 = expf(lg[0] - m), e1 = expf(lg[1] - m), e2 = expf(lg[2] - m);
    float s = e0 + e1 + e2;
    float p0 = e0 / s, p1 = e1 / s, p2 = e2 / s;
    float* f = flags + b * 16;
    f[0] = p0; f[1] = p1; f[2] = p2;
    float cn = (p1 > THRESH) ? 1.f : 0.f;               // neither local nor sparse
    float cl = (p0 + p1 > THRESH) ? 1.f : 0.f;          // local only
    float cs = (p1 + p2 > THRESH) ? 1.f : 0.f;          // sparse only
    float cls = (p0 + p1 + p2 > THRESH) ? 1.f : 0.f;    // both
    f[3] = cn; f[4] = cl; f[5] = cs; f[6] = cls;
    f[7] = ((cls != cl) || (cs != cn)) ? 1.f : 0.f;     // sparse mask matters
  }
}

// ---------------- QKV GEMM: x(4096,512) @ qkv_w^T(512,1536) -> q,k,v (B,H,L,hd)
__global__ __launch_bounds__(256) void qkv_gemm_kernel(
    const float* __restrict__ A, const float* __restrict__ W,
    float* __restrict__ qkv) {
  __shared__ float As[16][68];
  __shared__ float Bs[16][68];
  int t = threadIdx.x;
  int m0 = blockIdx.y * 64;
  int n0 = blockIdx.x * 64;
  int ty = t >> 4, tx = t & 15;
  int lr = t >> 2;
  int lc = (t & 3) << 2;
  float acc[4][4] = {};
  for (int k0 = 0; k0 < 512; k0 += 16) {
    float4 av = *(const float4*)(A + (size_t)(m0 + lr) * 512 + k0 + lc);
    float4 bv = *(const float4*)(W + (size_t)(n0 + lr) * 512 + k0 + lc);
    As[lc + 0][lr] = av.x; As[lc + 1][lr] = av.y; As[lc + 2][lr] = av.z; As[lc + 3][lr] = av.w;
    Bs[lc + 0][lr] = bv.x; Bs[lc + 1][lr] = bv.y; Bs[lc + 2][lr] = bv.z; Bs[lc + 3][lr] = bv.w;
    __syncthreads();
#pragma unroll
    for (int kk = 0; kk < 16; ++kk) {
      float4 a = *(const float4*)&As[kk][ty << 2];
      float4 bq = *(const float4*)&Bs[kk][tx << 2];
      float ar[4] = {a.x, a.y, a.z, a.w};
      float br[4] = {bq.x, bq.y, bq.z, bq.w};
#pragma unroll
      for (int i = 0; i < 4; ++i)
#pragma unroll
        for (int j = 0; j < 4; ++j) acc[i][j] = fmaf(ar[i], br[j], acc[i][j]);
    }
    __syncthreads();
  }
  // block spans exactly one (tsel,h) group of 64 columns
  int tsel = n0 >> 9;
  int h = (n0 & 511) >> 6;
  float* dst = qkv + (size_t)tsel * (NB * NH * SEQ * HDIM);
#pragma unroll
  for (int i = 0; i < 4; ++i) {
    int m = m0 + (ty << 2) + i;
    int bb = m >> 10, l = m & 1023;
    float* row = dst + ((size_t)(bb * NH + h) * SEQ + l) * HDIM;
#pragma unroll
    for (int j = 0; j < 4; ++j) row[(tx << 2) + j] = acc[i][j];
  }
}

// ---------------- proj GEMM: ao(4096,512) @ proj_w^T(512,512) + bias -> out
__global__ __launch_bounds__(256) void proj_gemm_kernel(
    const float* __restrict__ A, const float* __restrict__ W,
    const float* __restrict__ bias, float* __restrict__ out) {
  __shared__ float As[16][68];
  __shared__ float Bs[16][68];
  int t = threadIdx.x;
  int m0 = blockIdx.y * 64;
  int n0 = blockIdx.x * 64;
  int ty = t >> 4, tx = t & 15;
  int lr = t >> 2;
  int lc = (t & 3) << 2;
  float acc[4][4] = {};
  for (int k0 = 0; k0 < 512; k0 += 16) {
    float4 av = *(const float4*)(A + (size_t)(m0 + lr) * 512 + k0 + lc);
    float4 bv = *(const float4*)(W + (size_t)(n0 + lr) * 512 + k0 + lc);
    As[lc + 0][lr] = av.x; As[lc + 1][lr] = av.y; As[lc + 2][lr] = av.z; As[lc + 3][lr] = av.w;
    Bs[lc + 0][lr] = bv.x; Bs[lc + 1][lr] = bv.y; Bs[lc + 2][lr] = bv.z; Bs[lc + 3][lr] = bv.w;
    __syncthreads();
#pragma unroll
    for (int kk = 0; kk < 16; ++kk) {
      float4 a = *(const float4*)&As[kk][ty << 2];
      float4 bq = *(const float4*)&Bs[kk][tx << 2];
      float ar[4] = {a.x, a.y, a.z, a.w};
      float br[4] = {bq.x, bq.y, bq.z, bq.w};
#pragma unroll
      for (int i = 0; i < 4; ++i)
#pragma unroll
        for (int j = 0; j < 4; ++j) acc[i][j] = fmaf(ar[i], br[j], acc[i][j]);
    }
    __syncthreads();
  }
#pragma unroll
  for (int i = 0; i < 4; ++i) {
    int m = m0 + (ty << 2) + i;
#pragma unroll
    for (int j = 0; j < 4; ++j) {
      int n = n0 + (tx << 2) + j;
      out[(size_t)m * 512 + n] = acc[i][j] + bias[n];
    }
  }
}

// ---------------- banded attention (fast path: allow == local_mask [&& c_l]) ---
__global__ __launch_bounds__(256) void attn_banded_kernel(
    const float* __restrict__ flags,
    const float* __restrict__ qa, const float* __restrict__ ka,
    const float* __restrict__ va, float* __restrict__ ao) {
  int bid = blockIdx.x;                 // NB*NH*64 blocks, 16 q each
  int qb = bid & 63;
  int h = (bid >> 6) & 7;
  int b = bid >> 9;
  const float* f = flags + b * 16;
  if (f[7] > 0.5f || f[3] > 0.5f) return;   // generic kernel handles this sample
  int t = threadIdx.x;
  int q0 = qb << 4;
  size_t bh = (size_t)(b * NH + h) * SEQ * HDIM;

  if (f[4] < 0.5f) {
    // every row fully masked -> attn = one-hot at j=0 -> out = v[...,0,:]
    int d = t & 63;
    float val = va[bh + d];
    for (int qq = t >> 6; qq < 16; qq += 4)
      ao[((size_t)b * SEQ + q0 + qq) * DIM + h * HDIM + d] = val;
    return;
  }

  __shared__ float kx[48][65];
  __shared__ float vx[48][64];
  __shared__ float qx[16][64];
  __shared__ float px[16][48];

  int d = t & 63;
  for (int r = t >> 6; r < 48; r += 4) {
    int j = q0 - HALFW + r;
    bool ok = (j >= 0) && (j < SEQ);
    kx[r][d] = ok ? ka[bh + (size_t)j * HDIM + d] : 0.f;
    vx[r][d] = ok ? va[bh + (size_t)j * HDIM + d] : 0.f;
  }
  for (int r = t >> 6; r < 16; r += 4)
    qx[r][d] = qa[bh + (size_t)(q0 + r) * HDIM + d];
  __syncthreads();

  int w = t >> 6;
  int lane = t & 63;
  for (int qi = 0; qi < 4; ++qi) {
    int qq = w * 4 + qi;
    int q = q0 + qq;
    if (lane < 48) px[qq][lane] = 0.f;
    int j = q - HALFW + lane;
    bool valid = (lane <= 2 * HALFW) && (j >= 0) && (j < SEQ);
    int jb = qq + lane;       // j - (q0 - HALFW)
    float s = -INFINITY;
    if (valid) {
      float acc = 0.f;
#pragma unroll
      for (int dd = 0; dd < 64; ++dd) acc = fmaf(qx[qq][dd], kx[jb][dd], acc);
      s = acc * SCALE;
    }
    float m = s;
#pragma unroll
    for (int msk = 32; msk >= 1; msk >>= 1) m = fmaxf(m, __shfl_xor(m, msk));
    float p = valid ? expf(s - m) : 0.f;
    float sum = p;
#pragma unroll
    for (int msk = 32; msk >= 1; msk >>= 1) sum += __shfl_xor(sum, msk);
    p = p / sum;
    if (valid) px[qq][jb] = p;
    __syncthreads();
    float o = 0.f;
#pragma unroll 8
    for (int r = 0; r < 48; ++r) o = fmaf(px[qq][r], vx[r][lane], o);
    ao[((size_t)b * SEQ + q) * DIM + h * HDIM + lane] = o;
  }
}

// ---------------- generic fallback (sparse mask matters or global allowed) ----
__device__ __forceinline__ int block_sum_i(int v, int* red, int t) {
#pragma unroll
  for (int m = 32; m >= 1; m >>= 1) v += __shfl_xor(v, m);
  __syncthreads();
  if ((t & 63) == 0) red[t >> 6] = v;
  __syncthreads();
  return red[0] + red[1] + red[2] + red[3];
}
__device__ __forceinline__ float block_sum_f(float v, float* red, int t) {
#pragma unroll
  for (int m = 32; m >= 1; m >>= 1) v += __shfl_xor(v, m);
  __syncthreads();
  if ((t & 63) == 0) red[t >> 6] = v;
  __syncthreads();
  return red[0] + red[1] + red[2] + red[3];
}
__device__ __forceinline__ float block_max_f(float v, float* red, int t) {
#pragma unroll
  for (int m = 32; m >= 1; m >>= 1) v = fmaxf(v, __shfl_xor(v, m));
  __syncthreads();
  if ((t & 63) == 0) red[t >> 6] = v;
  __syncthreads();
  return fmaxf(fmaxf(red[0], red[1]), fmaxf(red[2], red[3]));
}

__global__ __launch_bounds__(256) void attn_generic_kernel(
    const float* __restrict__ flags,
    const float* __restrict__ qa, const float* __restrict__ ka,
    const float* __restrict__ va,
    const float* __restrict__ sw, const float* __restrict__ sb,
    float* __restrict__ ao) {
  int bid = blockIdx.x;            // NB*NH*256 blocks, 4 q each
  int qg = bid & 255;
  int h = (bid >> 8) & 7;
  int b = bid >> 11;
  const float* f = flags + b * 16;
  bool need_sparse = f[7] > 0.5f;
  bool cn_b = f[3] > 0.5f;
  if (!(need_sparse || cn_b)) return;   // banded kernel handled this sample

  int t = threadIdx.x;
  size_t bh = (size_t)(b * NH + h) * SEQ * HDIM;
  float c_n = f[3], c_l = f[4], c_s = f[5], c_ls = f[6];
  float swh = sw[h], sbh = sb[h];

  __shared__ float s_sh[SEQ];
  __shared__ float q_sh[HDIM];
  __shared__ unsigned u_sh[SEQ];
  __shared__ int sc_a[SEQ];
  __shared__ int sc_b[SEQ];
  __shared__ float redf[4];
  __shared__ int redi[4];

  for (int qi = 0; qi < 4; ++qi) {
    int q = qg * 4 + qi;
    if (t < HDIM) q_sh[t] = qa[bh + (size_t)q * HDIM + t];
    __syncthreads();
    for (int j = t; j < SEQ; j += 256) {
      const float* kr = ka + bh + (size_t)j * HDIM;
      float acc = 0.f;
#pragma unroll
      for (int dd = 0; dd < HDIM; ++dd) acc = fmaf(q_sh[dd], kr[dd], acc);
      s_sh[j] = acc * SCALE;
    }
    __syncthreads();

    if (need_sparse) {
      // monotone uint mapping of s2 = s*sw[h]+sb[h]
      for (int j = t; j < SEQ; j += 256) {
        unsigned bits = __float_as_uint(fmaf(s_sh[j], swh, sbh));
        u_sh[j] = bits ^ ((bits & 0x80000000u) ? 0xFFFFFFFFu : 0x80000000u);
      }
      __syncthreads();
      // V = KTOP-th largest (largest T with count(u>=T) >= KTOP)
      unsigned V = 0u;
      for (int bit = 31; bit >= 0; --bit) {
        unsigned cand = V | (1u << bit);
        int c = 0;
        for (int j = t; j < SEQ; j += 256) c += (u_sh[j] >= cand) ? 1 : 0;
        c = block_sum_i(c, redi, t);
        if (c >= KTOP) V = cand;
      }
      int g = 0;
      for (int j = t; j < SEQ; j += 256) g += (u_sh[j] > V) ? 1 : 0;
      g = block_sum_i(g, redi, t);
      int r = KTOP - g;   // equals admitted, lowest index first
      for (int j = t; j < SEQ; j += 256) sc_a[j] = (u_sh[j] == V) ? 1 : 0;
      __syncthreads();
      int* src = sc_a; int* dst = sc_b;
      for (int off = 1; off < SEQ; off <<= 1) {
        for (int j = t; j < SEQ; j += 256)
          dst[j] = src[j] + ((j >= off) ? src[j - off] : 0);
        __syncthreads();
        int* tmp = src; src = dst; dst = tmp;
      }
      for (int j = t; j < SEQ; j += 256) {
        bool sp = (u_sh[j] > V) || ((u_sh[j] == V) && (src[j] - 1 < r));
        bool local = (j >= q - HALFW) && (j <= q + HALFW);
        float cv = local ? (sp ? c_ls : c_l) : (sp ? c_s : c_n);
        if (cv < 0.5f) s_sh[j] = -INFINITY;
      }
    } else {
      for (int j = t; j < SEQ; j += 256) {
        bool local = (j >= q - HALFW) && (j <= q + HALFW);
        float cv = local ? c_l : c_n;
        if (cv < 0.5f) s_sh[j] = -INFINITY;
      }
    }
    __syncthreads();

    int anyc = 0;
    for (int j = t; j < SEQ; j += 256) anyc += (s_sh[j] != -INFINITY) ? 1 : 0;
    anyc = block_sum_i(anyc, redi, t);
    if (anyc == 0 && t == 0) s_sh[0] = 0.f;
    __syncthreads();

    float mx = -INFINITY;
    for (int j = t; j < SEQ; j += 256) mx = fmaxf(mx, s_sh[j]);
    mx = block_max_f(mx, redf, t);
    float ls = 0.f;
    for (int j = t; j < SEQ; j += 256) {
      float p = (s_sh[j] == -INFINITY) ? 0.f : expf(s_sh[j] - mx);
      s_sh[j] = p; ls += p;
    }
    ls = block_sum_f(ls, redf, t);   // internal barriers make s_sh writes visible
    float inv = 1.f / ls;

    int dd = t & 63, jg = t >> 6;
    float acc = 0.f;
    for (int j = jg; j < SEQ; j += 4)
      acc = fmaf(s_sh[j] * inv, va[bh + (size_t)j * HDIM + dd], acc);
    float* redo = (float*)u_sh;
    __syncthreads();
    redo[t] = acc;
    __syncthreads();
    if (t < 64) {
      float o = redo[t] + redo[t + 64] + redo[t + 128] + redo[t + 192];
      ao[((size_t)b * SEQ + q) * DIM + h * HDIM + t] = o;
    }
    __syncthreads();
  }
}

extern "C" void kernel_launch(void* const* d_in, const int* in_sizes, int n_in,
                              void* d_out, int out_size, void* d_ws, size_t ws_size,
                              hipStream_t stream) {
  const float* x      = (const float*)d_in[0];
  const float* qkv_w  = (const float*)d_in[1];
  const float* proj_w = (const float*)d_in[2];
  const float* proj_b = (const float*)d_in[3];
  const float* ps_w1  = (const float*)d_in[4];
  const float* ps_b1  = (const float*)d_in[5];
  const float* ps_w2  = (const float*)d_in[6];
  const float* ps_b2  = (const float*)d_in[7];
  const float* ps_w3  = (const float*)d_in[8];
  const float* ps_b3  = (const float*)d_in[9];
  const float* pbias  = (const float*)d_in[10];
  const float* sw     = (const float*)d_in[11];
  const float* sb     = (const float*)d_in[12];
  float* out = (float*)d_out;

  float* ws = (float*)d_ws;
  float* flags   = ws;                               // 64 floats
  float* partial = ws + 64;                          // NB*32*DIM = 65536
  float* qkv     = partial + NB * 32 * DIM;          // 3 * 2097152
  float* qa = qkv;
  float* ka = qa + (size_t)NB * NH * SEQ * HDIM;
  float* va = ka + (size_t)NB * NH * SEQ * HDIM;
  float* ao = va + (size_t)NB * NH * SEQ * HDIM;     // 2097152

  hipLaunchKernelGGL(partial_pool_kernel, dim3(NB * 32), dim3(256), 0, stream,
                     x, partial);
  hipLaunchKernelGGL(selector_mlp_kernel, dim3(NB), dim3(256), 0, stream,
                     partial, ps_w1, ps_b1, ps_w2, ps_b2, ps_w3, ps_b3, pbias, flags);
  hipLaunchKernelGGL(qkv_gemm_kernel, dim3(1536 / 64, 4096 / 64), dim3(256), 0, stream,
                     x, qkv_w, qkv);
  hipLaunchKernelGGL(attn_banded_kernel, dim3(NB * NH * (SEQ / 16)), dim3(256), 0, stream,
                     flags, qa, ka, va, ao);
  hipLaunchKernelGGL(attn_generic_kernel, dim3(NB * NH * (SEQ / 4)), dim3(256), 0, stream,
                     flags, qa, ka, va, sw, sb, ao);
  hipLaunchKernelGGL(proj_gemm_kernel, dim3(512 / 64, 4096 / 64), dim3(256), 0, stream,
                     ao, proj_w, proj_b, out);
}

// Round 2
// 214.941 us; speedup vs baseline: 1.3936x; 1.3936x over previous
//
#include <hip/hip_runtime.h>
#include <hip/hip_bf16.h>
#include <math.h>

#define NB 4
#define SEQ 1024
#define DIM 512
#define NH 8
#define HDIM 64
#define HALFW 16
#define KTOP 716
#define THRESH 0.05f
#define PATT 0.3f
#define SCALE 0.125f
#define QKVN 1536

typedef __attribute__((ext_vector_type(8))) short bf16x8;
typedef __attribute__((ext_vector_type(4))) float f32x4;

__device__ __forceinline__ void async_load16(const void* g, void* l) {
  __builtin_amdgcn_global_load_lds(
      (const __attribute__((address_space(1))) void*)g,
      (__attribute__((address_space(3))) void*)l, 16, 0, 0);
}

// ---------------- fp32 -> bf16 conversion (x, qkv_w, proj_w in one launch) ---
__global__ __launch_bounds__(256) void cvt_all_kernel(
    const float* __restrict__ x, const float* __restrict__ wq,
    const float* __restrict__ wp,
    __hip_bfloat16* __restrict__ xb, __hip_bfloat16* __restrict__ wqb,
    __hip_bfloat16* __restrict__ wpb) {
  int i = blockIdx.x * 256 + threadIdx.x;   // indexes 8-float groups
  const float* s;
  __hip_bfloat16* d;
  if (i < 262144) { s = x + (size_t)i * 8; d = xb + (size_t)i * 8; }
  else if (i < 360448) { int j = i - 262144; s = wq + (size_t)j * 8; d = wqb + (size_t)j * 8; }
  else { int j = i - 360448; s = wp + (size_t)j * 8; d = wpb + (size_t)j * 8; }
  float4 a = *(const float4*)s;
  float4 b = *(const float4*)(s + 4);
  union { __hip_bfloat16 h[8]; uint4 u; } o;
  o.h[0] = __float2bfloat16(a.x); o.h[1] = __float2bfloat16(a.y);
  o.h[2] = __float2bfloat16(a.z); o.h[3] = __float2bfloat16(a.w);
  o.h[4] = __float2bfloat16(b.x); o.h[5] = __float2bfloat16(b.y);
  o.h[6] = __float2bfloat16(b.z); o.h[7] = __float2bfloat16(b.w);
  *(uint4*)d = o.u;
}

// ---------------- MFMA GEMM: C(MxN) = A(MxK) @ B(NxK)^T [+ bias] -------------
// m97 structure: 128x128 tile, BK=32, global_load_lds width 16, 4 waves,
// each wave 64x64 via 4x4 grid of 16x16x32 bf16 MFMA.
__global__ __launch_bounds__(256) void gemm_bt_bf16_kernel(
    const __hip_bfloat16* __restrict__ A, const __hip_bfloat16* __restrict__ B,
    const float* __restrict__ bias, float* __restrict__ C,
    int N, int K) {
  __shared__ __hip_bfloat16 As[128 * 32];
  __shared__ __hip_bfloat16 Bs[128 * 32];
  int t = threadIdx.x;
  int m0 = blockIdx.y * 128;
  int n0 = blockIdx.x * 128;
  int w = t >> 6, l = t & 63;
  int wr = w >> 1, wc = w & 1;
  int fm = l & 15, fg = l >> 4;   // fragment: m/n = fm, k-group = fg
  f32x4 acc[4][4] = {};

  for (int k0 = 0; k0 < K; k0 += 32) {
#pragma unroll
    for (int i = 0; i < 2; ++i) {
      int s = i * 256 + t;
      int row = s >> 2;
      int cb = (s & 3) << 4;      // byte offset within a 64-byte (32 bf16) row
      const char* ga = (const char*)(A + (size_t)(m0 + row) * K + k0) + cb;
      const char* gb = (const char*)(B + (size_t)(n0 + row) * K + k0) + cb;
      async_load16(ga, (char*)As + (size_t)s * 16);
      async_load16(gb, (char*)Bs + (size_t)s * 16);
    }
    __syncthreads();   // compiler emits vmcnt(0) drain before barrier
    bf16x8 af[4], bf[4];
#pragma unroll
    for (int i = 0; i < 4; ++i)
      af[i] = *(const bf16x8*)(As + (size_t)(wr * 64 + i * 16 + fm) * 32 + fg * 8);
#pragma unroll
    for (int j = 0; j < 4; ++j)
      bf[j] = *(const bf16x8*)(Bs + (size_t)(wc * 64 + j * 16 + fm) * 32 + fg * 8);
#pragma unroll
    for (int i = 0; i < 4; ++i)
#pragma unroll
      for (int j = 0; j < 4; ++j)
        acc[i][j] = __builtin_amdgcn_mfma_f32_16x16x32_bf16(af[i], bf[j], acc[i][j], 0, 0, 0);
    __syncthreads();
  }
  // epilogue: C/D layout col=lane&15, row=(lane>>4)*4+reg  [m89-verified]
#pragma unroll
  for (int i = 0; i < 4; ++i) {
    int mbase = m0 + wr * 64 + i * 16 + fg * 4;
#pragma unroll
    for (int j = 0; j < 4; ++j) {
      int n = n0 + wc * 64 + j * 16 + fm;
      float bv = bias ? bias[n] : 0.f;
#pragma unroll
      for (int r = 0; r < 4; ++r)
        C[(size_t)(mbase + r) * N + n] = acc[i][j][r] + bv;
    }
  }
}

// ---------------- selector: partial pooling ----------------
__global__ __launch_bounds__(256) void partial_pool_kernel(
    const float* __restrict__ x, float* __restrict__ partial) {
  int bid = blockIdx.x;          // NB*32
  int b = bid >> 5, c = bid & 31;
  int t = threadIdx.x;
  const float* xb = x + ((size_t)b * SEQ + (size_t)c * 32) * DIM;
  for (int d = t; d < DIM; d += 256) {
    float acc = 0.f;
#pragma unroll 8
    for (int ll = 0; ll < 32; ++ll) acc += xb[(size_t)ll * DIM + d];
    partial[(size_t)bid * DIM + d] = acc;
  }
}

// ---------------- selector: MLP + flags ----------------
__global__ __launch_bounds__(256) void selector_mlp_kernel(
    const float* __restrict__ partial,
    const float* __restrict__ w1, const float* __restrict__ b1,
    const float* __restrict__ w2, const float* __restrict__ b2,
    const float* __restrict__ w3, const float* __restrict__ b3,
    const float* __restrict__ pbias, float* __restrict__ flags) {
  int b = blockIdx.x;
  int t = threadIdx.x;
  __shared__ float pooled[DIM];
  __shared__ float h1[DIM];
  __shared__ float h2[DIM / 2];
  __shared__ float lg[3];
  for (int d = t; d < DIM; d += 256) {
    float acc = 0.f;
    for (int c = 0; c < 32; ++c) acc += partial[(size_t)(b * 32 + c) * DIM + d];
    pooled[d] = acc * (1.0f / SEQ);
  }
  __syncthreads();
  for (int i = t; i < DIM; i += 256) {
    float acc = b1[i];
    const float* w = w1 + (size_t)i * DIM;
    for (int k = 0; k < DIM; ++k) acc = fmaf(pooled[k], w[k], acc);
    h1[i] = fmaxf(acc, 0.f);
  }
  __syncthreads();
  for (int i = t; i < DIM / 2; i += 256) {
    float acc = b2[i];
    const float* w = w2 + (size_t)i * DIM;
    for (int k = 0; k < DIM; ++k) acc = fmaf(h1[k], w[k], acc);
    h2[i] = fmaxf(acc, 0.f);
  }
  __syncthreads();
  if (t < 3) {
    float acc = b3[t] + pbias[t];
    const float* w = w3 + t * (DIM / 2);
    for (int k = 0; k < DIM / 2; ++k) acc = fmaf(h2[k], w[k], acc);
    lg[t] = acc * (1.0f / PATT);
  }
  __syncthreads();
  if (t == 0) {
    float m = fmaxf(lg[0], fmaxf(lg[1], lg[2]));
    float e0 = expf(lg[0] - m), e1 = expf(lg[1] - m), e2 = expf(lg[2] - m);
    float s = e0 + e1 + e2;
    float p0 = e0 / s, p1 = e1 / s, p2 = e2 / s;
    float* f = flags + b * 16;
    f[0] = p0; f[1] = p1; f[2] = p2;
    float cn = (p1 > THRESH) ? 1.f : 0.f;
    float cl = (p0 + p1 > THRESH) ? 1.f : 0.f;
    float cs = (p1 + p2 > THRESH) ? 1.f : 0.f;
    float cls = (p0 + p1 + p2 > THRESH) ? 1.f : 0.f;
    f[3] = cn; f[4] = cl; f[5] = cs; f[6] = cls;
    f[7] = ((cls != cl) || (cs != cn)) ? 1.f : 0.f;   // sparse mask matters
  }
}

// qkv layout: fp32, (B*SEQ) x 1536 row-major; q at +0, k at +512, v at +1024
// within each row; per-head offset h*64.

// ---------------- banded attention (fast path) ----------------
__global__ __launch_bounds__(256) void attn_banded_kernel(
    const float* __restrict__ flags, const float* __restrict__ qkv,
    __hip_bfloat16* __restrict__ ao) {
  int bid = blockIdx.x;                 // NB*NH*64 blocks, 16 q each
  int qb = bid & 63;
  int h = (bid >> 6) & 7;
  int b = bid >> 9;
  const float* f = flags + b * 16;
  if (f[7] > 0.5f || f[3] > 0.5f) return;   // generic kernel handles this sample
  int t = threadIdx.x;
  int q0 = qb << 4;
  const float* base = qkv + (size_t)b * SEQ * QKVN;
  int ho = h * HDIM;

  if (f[4] < 0.5f) {
    // every row fully masked -> one-hot at j=0 -> out = v[...,0,:]
    int d = t & 63;
    float val = base[1024 + ho + d];
    for (int qq = t >> 6; qq < 16; qq += 4)
      ao[((size_t)b * SEQ + q0 + qq) * DIM + ho + d] = __float2bfloat16(val);
    return;
  }

  __shared__ float kx[48][65];
  __shared__ float vx[48][64];
  __shared__ float qx[16][64];
  __shared__ float px[16][48];

  int d = t & 63;
  for (int r = t >> 6; r < 48; r += 4) {
    int j = q0 - HALFW + r;
    bool ok = (j >= 0) && (j < SEQ);
    kx[r][d] = ok ? base[(size_t)j * QKVN + 512 + ho + d] : 0.f;
    vx[r][d] = ok ? base[(size_t)j * QKVN + 1024 + ho + d] : 0.f;
  }
  for (int r = t >> 6; r < 16; r += 4)
    qx[r][d] = base[(size_t)(q0 + r) * QKVN + ho + d];
  __syncthreads();

  int w = t >> 6;
  int lane = t & 63;
  for (int qi = 0; qi < 4; ++qi) {
    int qq = w * 4 + qi;
    int q = q0 + qq;
    if (lane < 48) px[qq][lane] = 0.f;
    int j = q - HALFW + lane;
    bool valid = (lane <= 2 * HALFW) && (j >= 0) && (j < SEQ);
    int jb = qq + lane;
    float s = -INFINITY;
    if (valid) {
      float acc = 0.f;
#pragma unroll
      for (int dd = 0; dd < 64; ++dd) acc = fmaf(qx[qq][dd], kx[jb][dd], acc);
      s = acc * SCALE;
    }
    float m = s;
#pragma unroll
    for (int msk = 32; msk >= 1; msk >>= 1) m = fmaxf(m, __shfl_xor(m, msk));
    float p = valid ? expf(s - m) : 0.f;
    float sum = p;
#pragma unroll
    for (int msk = 32; msk >= 1; msk >>= 1) sum += __shfl_xor(sum, msk);
    p = p / sum;
    if (valid) px[qq][jb] = p;
    __syncthreads();
    float o = 0.f;
#pragma unroll 8
    for (int r = 0; r < 48; ++r) o = fmaf(px[qq][r], vx[r][lane], o);
    ao[((size_t)b * SEQ + q) * DIM + ho + lane] = __float2bfloat16(o);
  }
}

// ---------------- generic fallback ----------------
__device__ __forceinline__ int block_sum_i(int v, int* red, int t) {
#pragma unroll
  for (int m = 32; m >= 1; m >>= 1) v += __shfl_xor(v, m);
  __syncthreads();
  if ((t & 63) == 0) red[t >> 6] = v;
  __syncthreads();
  return red[0] + red[1] + red[2] + red[3];
}
__device__ __forceinline__ float block_sum_f(float v, float* red, int t) {
#pragma unroll
  for (int m = 32; m >= 1; m >>= 1) v += __shfl_xor(v, m);
  __syncthreads();
  if ((t & 63) == 0) red[t >> 6] = v;
  __syncthreads();
  return red[0] + red[1] + red[2] + red[3];
}
__device__ __forceinline__ float block_max_f(float v, float* red, int t) {
#pragma unroll
  for (int m = 32; m >= 1; m >>= 1) v = fmaxf(v, __shfl_xor(v, m));
  __syncthreads();
  if ((t & 63) == 0) red[t >> 6] = v;
  __syncthreads();
  return fmaxf(fmaxf(red[0], red[1]), fmaxf(red[2], red[3]));
}

__global__ __launch_bounds__(256) void attn_generic_kernel(
    const float* __restrict__ flags, const float* __restrict__ qkv,
    const float* __restrict__ sw, const float* __restrict__ sb,
    __hip_bfloat16* __restrict__ ao) {
  int bid = blockIdx.x;            // NB*NH*256 blocks, 4 q each
  int qg = bid & 255;
  int h = (bid >> 8) & 7;
  int b = bid >> 11;
  const float* f = flags + b * 16;
  bool need_sparse = f[7] > 0.5f;
  bool cn_b = f[3] > 0.5f;
  if (!(need_sparse || cn_b)) return;   // banded kernel handled this sample

  int t = threadIdx.x;
  const float* base = qkv + (size_t)b * SEQ * QKVN;
  int ho = h * HDIM;
  float c_n = f[3], c_l = f[4], c_s = f[5], c_ls = f[6];
  float swh = sw[h], sbh = sb[h];

  __shared__ float s_sh[SEQ];
  __shared__ float q_sh[HDIM];
  __shared__ unsigned u_sh[SEQ];
  __shared__ int sc_a[SEQ];
  __shared__ int sc_b[SEQ];
  __shared__ float redf[4];
  __shared__ int redi[4];

  for (int qi = 0; qi < 4; ++qi) {
    int q = qg * 4 + qi;
    if (t < HDIM) q_sh[t] = base[(size_t)q * QKVN + ho + t];
    __syncthreads();
    for (int j = t; j < SEQ; j += 256) {
      const float* kr = base + (size_t)j * QKVN + 512 + ho;
      float acc = 0.f;
#pragma unroll
      for (int dd = 0; dd < HDIM; ++dd) acc = fmaf(q_sh[dd], kr[dd], acc);
      s_sh[j] = acc * SCALE;
    }
    __syncthreads();

    if (need_sparse) {
      for (int j = t; j < SEQ; j += 256) {
        unsigned bits = __float_as_uint(fmaf(s_sh[j], swh, sbh));
        u_sh[j] = bits ^ ((bits & 0x80000000u) ? 0xFFFFFFFFu : 0x80000000u);
      }
      __syncthreads();
      unsigned V = 0u;
      for (int bit = 31; bit >= 0; --bit) {
        unsigned cand = V | (1u << bit);
        int c = 0;
        for (int j = t; j < SEQ; j += 256) c += (u_sh[j] >= cand) ? 1 : 0;
        c = block_sum_i(c, redi, t);
        if (c >= KTOP) V = cand;
      }
      int g = 0;
      for (int j = t; j < SEQ; j += 256) g += (u_sh[j] > V) ? 1 : 0;
      g = block_sum_i(g, redi, t);
      int r = KTOP - g;
      for (int j = t; j < SEQ; j += 256) sc_a[j] = (u_sh[j] == V) ? 1 : 0;
      __syncthreads();
      int* src = sc_a; int* dst = sc_b;
      for (int off = 1; off < SEQ; off <<= 1) {
        for (int j = t; j < SEQ; j += 256)
          dst[j] = src[j] + ((j >= off) ? src[j - off] : 0);
        __syncthreads();
        int* tmp = src; src = dst; dst = tmp;
      }
      for (int j = t; j < SEQ; j += 256) {
        bool sp = (u_sh[j] > V) || ((u_sh[j] == V) && (src[j] - 1 < r));
        bool local = (j >= q - HALFW) && (j <= q + HALFW);
        float cv = local ? (sp ? c_ls : c_l) : (sp ? c_s : c_n);
        if (cv < 0.5f) s_sh[j] = -INFINITY;
      }
    } else {
      for (int j = t; j < SEQ; j += 256) {
        bool local = (j >= q - HALFW) && (j <= q + HALFW);
        float cv = local ? c_l : c_n;
        if (cv < 0.5f) s_sh[j] = -INFINITY;
      }
    }
    __syncthreads();

    int anyc = 0;
    for (int j = t; j < SEQ; j += 256) anyc += (s_sh[j] != -INFINITY) ? 1 : 0;
    anyc = block_sum_i(anyc, redi, t);
    if (anyc == 0 && t == 0) s_sh[0] = 0.f;
    __syncthreads();

    float mx = -INFINITY;
    for (int j = t; j < SEQ; j += 256) mx = fmaxf(mx, s_sh[j]);
    mx = block_max_f(mx, redf, t);
    float ls = 0.f;
    for (int j = t; j < SEQ; j += 256) {
      float p = (s_sh[j] == -INFINITY) ? 0.f : expf(s_sh[j] - mx);
      s_sh[j] = p; ls += p;
    }
    ls = block_sum_f(ls, redf, t);
    float inv = 1.f / ls;

    int dd = t & 63, jg = t >> 6;
    float acc = 0.f;
    for (int j = jg; j < SEQ; j += 4)
      acc = fmaf(s_sh[j] * inv, base[(size_t)j * QKVN + 1024 + ho + dd], acc);
    float* redo = (float*)u_sh;
    __syncthreads();
    redo[t] = acc;
    __syncthreads();
    if (t < 64) {
      float o = redo[t] + redo[t + 64] + redo[t + 128] + redo[t + 192];
      ao[((size_t)b * SEQ + q) * DIM + ho + t] = __float2bfloat16(o);
    }
    __syncthreads();
  }
}

extern "C" void kernel_launch(void* const* d_in, const int* in_sizes, int n_in,
                              void* d_out, int out_size, void* d_ws, size_t ws_size,
                              hipStream_t stream) {
  const float* x      = (const float*)d_in[0];
  const float* qkv_w  = (const float*)d_in[1];
  const float* proj_w = (const float*)d_in[2];
  const float* proj_b = (const float*)d_in[3];
  const float* ps_w1  = (const float*)d_in[4];
  const float* ps_b1  = (const float*)d_in[5];
  const float* ps_w2  = (const float*)d_in[6];
  const float* ps_b2  = (const float*)d_in[7];
  const float* ps_w3  = (const float*)d_in[8];
  const float* ps_b3  = (const float*)d_in[9];
  const float* pbias  = (const float*)d_in[10];
  const float* sw     = (const float*)d_in[11];
  const float* sb     = (const float*)d_in[12];
  float* out = (float*)d_out;

  char* w = (char*)d_ws;
  float* flags = (float*)w;              w += 256;
  float* partial = (float*)w;            w += (size_t)NB * 32 * DIM * 4;
  float* qkv = (float*)w;                w += (size_t)NB * SEQ * QKVN * 4;
  __hip_bfloat16* xb  = (__hip_bfloat16*)w;  w += (size_t)NB * SEQ * DIM * 2;
  __hip_bfloat16* wqb = (__hip_bfloat16*)w;  w += (size_t)QKVN * DIM * 2;
  __hip_bfloat16* wpb = (__hip_bfloat16*)w;  w += (size_t)DIM * DIM * 2;
  __hip_bfloat16* aob = (__hip_bfloat16*)w;  w += (size_t)NB * SEQ * DIM * 2;

  hipLaunchKernelGGL(cvt_all_kernel, dim3(1536), dim3(256), 0, stream,
                     x, qkv_w, proj_w, xb, wqb, wpb);
  hipLaunchKernelGGL(partial_pool_kernel, dim3(NB * 32), dim3(256), 0, stream,
                     x, partial);
  hipLaunchKernelGGL(selector_mlp_kernel, dim3(NB), dim3(256), 0, stream,
                     partial, ps_w1, ps_b1, ps_w2, ps_b2, ps_w3, ps_b3, pbias, flags);
  hipLaunchKernelGGL(gemm_bt_bf16_kernel, dim3(QKVN / 128, (NB * SEQ) / 128), dim3(256), 0, stream,
                     xb, wqb, (const float*)nullptr, qkv, QKVN, DIM);
  hipLaunchKernelGGL(attn_banded_kernel, dim3(NB * NH * (SEQ / 16)), dim3(256), 0, stream,
                     flags, qkv, aob);
  hipLaunchKernelGGL(attn_generic_kernel, dim3(NB * NH * (SEQ / 4)), dim3(256), 0, stream,
                     flags, qkv, sw, sb, aob);
  hipLaunchKernelGGL(gemm_bt_bf16_kernel, dim3(DIM / 128, (NB * SEQ) / 128), dim3(256), 0, stream,
                     aob, wpb, proj_b, out, DIM, DIM);
}

// Round 3
// 173.093 us; speedup vs baseline: 1.7305x; 1.2418x over previous
//
#include <hip/hip_runtime.h>
#include <hip/hip_bf16.h>
#include <math.h>

#define NB 4
#define SEQ 1024
#define DIM 512
#define NH 8
#define HDIM 64
#define HALFW 16
#define KTOP 716
#define THRESH 0.05f
#define PATT 0.3f
#define SCALE 0.125f
#define QKVN 1536

typedef __attribute__((ext_vector_type(8))) short bf16x8;
typedef __attribute__((ext_vector_type(4))) float f32x4;

__device__ __forceinline__ void async_load16(const void* g, void* l) {
  __builtin_amdgcn_global_load_lds(
      (const __attribute__((address_space(1))) void*)g,
      (__attribute__((address_space(3))) void*)l, 16, 0, 0);
}

// ---------------- fp32 -> bf16 conversion (x, qkv_w, proj_w in one launch) ---
__global__ __launch_bounds__(256) void cvt_all_kernel(
    const float* __restrict__ x, const float* __restrict__ wq,
    const float* __restrict__ wp,
    __hip_bfloat16* __restrict__ xb, __hip_bfloat16* __restrict__ wqb,
    __hip_bfloat16* __restrict__ wpb) {
  int i = blockIdx.x * 256 + threadIdx.x;   // indexes 8-float groups
  const float* s;
  __hip_bfloat16* d;
  if (i < 262144) { s = x + (size_t)i * 8; d = xb + (size_t)i * 8; }
  else if (i < 360448) { int j = i - 262144; s = wq + (size_t)j * 8; d = wqb + (size_t)j * 8; }
  else { int j = i - 360448; s = wp + (size_t)j * 8; d = wpb + (size_t)j * 8; }
  float4 a = *(const float4*)s;
  float4 b = *(const float4*)(s + 4);
  union { __hip_bfloat16 h[8]; uint4 u; } o;
  o.h[0] = __float2bfloat16(a.x); o.h[1] = __float2bfloat16(a.y);
  o.h[2] = __float2bfloat16(a.z); o.h[3] = __float2bfloat16(a.w);
  o.h[4] = __float2bfloat16(b.x); o.h[5] = __float2bfloat16(b.y);
  o.h[6] = __float2bfloat16(b.z); o.h[7] = __float2bfloat16(b.w);
  *(uint4*)d = o.u;
}

// ---------------- MFMA GEMM: C(MxN) = A(MxK) @ B(NxK)^T [+ bias] -------------
__global__ __launch_bounds__(256) void gemm_bt_bf16_kernel(
    const __hip_bfloat16* __restrict__ A, const __hip_bfloat16* __restrict__ B,
    const float* __restrict__ bias, float* __restrict__ C,
    int N, int K) {
  __shared__ __hip_bfloat16 As[128 * 32];
  __shared__ __hip_bfloat16 Bs[128 * 32];
  int t = threadIdx.x;
  int m0 = blockIdx.y * 128;
  int n0 = blockIdx.x * 128;
  int w = t >> 6, l = t & 63;
  int wr = w >> 1, wc = w & 1;
  int fm = l & 15, fg = l >> 4;
  f32x4 acc[4][4] = {};

  for (int k0 = 0; k0 < K; k0 += 32) {
#pragma unroll
    for (int i = 0; i < 2; ++i) {
      int s = i * 256 + t;
      int row = s >> 2;
      int cb = (s & 3) << 4;
      const char* ga = (const char*)(A + (size_t)(m0 + row) * K + k0) + cb;
      const char* gb = (const char*)(B + (size_t)(n0 + row) * K + k0) + cb;
      async_load16(ga, (char*)As + (size_t)s * 16);
      async_load16(gb, (char*)Bs + (size_t)s * 16);
    }
    __syncthreads();
    bf16x8 af[4], bf[4];
#pragma unroll
    for (int i = 0; i < 4; ++i)
      af[i] = *(const bf16x8*)(As + (size_t)(wr * 64 + i * 16 + fm) * 32 + fg * 8);
#pragma unroll
    for (int j = 0; j < 4; ++j)
      bf[j] = *(const bf16x8*)(Bs + (size_t)(wc * 64 + j * 16 + fm) * 32 + fg * 8);
#pragma unroll
    for (int i = 0; i < 4; ++i)
#pragma unroll
      for (int j = 0; j < 4; ++j)
        acc[i][j] = __builtin_amdgcn_mfma_f32_16x16x32_bf16(af[i], bf[j], acc[i][j], 0, 0, 0);
    __syncthreads();
  }
#pragma unroll
  for (int i = 0; i < 4; ++i) {
    int mbase = m0 + wr * 64 + i * 16 + fg * 4;
#pragma unroll
    for (int j = 0; j < 4; ++j) {
      int n = n0 + wc * 64 + j * 16 + fm;
      float bv = bias ? bias[n] : 0.f;
#pragma unroll
      for (int r = 0; r < 4; ++r)
        C[(size_t)(mbase + r) * N + n] = acc[i][j][r] + bv;
    }
  }
}

// ---------------- selector: partial pooling (128 blocks) ----------------
__global__ __launch_bounds__(256) void partial_pool_kernel(
    const float* __restrict__ x, float* __restrict__ partial) {
  int bid = blockIdx.x;          // NB*32
  int b = bid >> 5, c = bid & 31;
  int t = threadIdx.x;
  const float* xb = x + ((size_t)b * SEQ + (size_t)c * 32) * DIM;
  for (int d = t; d < DIM; d += 256) {
    float acc = 0.f;
#pragma unroll 8
    for (int ll = 0; ll < 32; ++ll) acc += xb[(size_t)ll * DIM + d];
    partial[(size_t)bid * DIM + d] = acc;
  }
}

// ---------------- selector: finish pooling (8 blocks) ----------------
__global__ __launch_bounds__(256) void pool_finish_kernel(
    const float* __restrict__ partial, float* __restrict__ pooled) {
  int i = blockIdx.x * 256 + threadIdx.x;   // 2048 = NB*DIM
  int b = i >> 9, d = i & 511;
  float acc = 0.f;
#pragma unroll 8
  for (int c = 0; c < 32; ++c) acc += partial[(size_t)(b * 32 + c) * DIM + d];
  pooled[i] = acc * (1.0f / SEQ);
}

// ---------------- selector: layer 1 — one wave per output (512 blocks) -------
__global__ __launch_bounds__(256) void mlp1_kernel(
    const float* __restrict__ pooled, const float* __restrict__ w1,
    const float* __restrict__ b1, float* __restrict__ h1) {
  int gw = blockIdx.x * 4 + (threadIdx.x >> 6);   // 2048 waves
  int lane = threadIdx.x & 63;
  int b = gw >> 9, i = gw & 511;
  const float* p = pooled + (size_t)b * DIM + lane * 8;
  const float* w = w1 + (size_t)i * DIM + lane * 8;
  float4 p0 = *(const float4*)p;
  float4 p1 = *(const float4*)(p + 4);
  float4 w0 = *(const float4*)w;
  float4 wv = *(const float4*)(w + 4);
  float acc = fmaf(p0.x, w0.x, fmaf(p0.y, w0.y, fmaf(p0.z, w0.z, p0.w * w0.w)));
  acc = fmaf(p1.x, wv.x, fmaf(p1.y, wv.y, fmaf(p1.z, wv.z, fmaf(p1.w, wv.w, acc))));
#pragma unroll
  for (int m = 32; m >= 1; m >>= 1) acc += __shfl_xor(acc, m);
  if (lane == 0) h1[gw] = fmaxf(acc + b1[i], 0.f);
}

// ---------------- selector: layer 2 — one wave per output (256 blocks) -------
__global__ __launch_bounds__(256) void mlp2_kernel(
    const float* __restrict__ h1, const float* __restrict__ w2,
    const float* __restrict__ b2, float* __restrict__ h2) {
  int gw = blockIdx.x * 4 + (threadIdx.x >> 6);   // 1024 waves
  int lane = threadIdx.x & 63;
  int b = gw >> 8, i = gw & 255;
  const float* p = h1 + (size_t)b * DIM + lane * 8;
  const float* w = w2 + (size_t)i * DIM + lane * 8;
  float4 p0 = *(const float4*)p;
  float4 p1 = *(const float4*)(p + 4);
  float4 w0 = *(const float4*)w;
  float4 wv = *(const float4*)(w + 4);
  float acc = fmaf(p0.x, w0.x, fmaf(p0.y, w0.y, fmaf(p0.z, w0.z, p0.w * w0.w)));
  acc = fmaf(p1.x, wv.x, fmaf(p1.y, wv.y, fmaf(p1.z, wv.z, fmaf(p1.w, wv.w, acc))));
#pragma unroll
  for (int m = 32; m >= 1; m >>= 1) acc += __shfl_xor(acc, m);
  if (lane == 0) h2[gw] = fmaxf(acc + b2[i], 0.f);
}

// ---------------- selector: logits + softmax + flags (4 blocks × 1 wave) -----
__global__ __launch_bounds__(64) void mlp3_flags_kernel(
    const float* __restrict__ h2, const float* __restrict__ w3,
    const float* __restrict__ b3, const float* __restrict__ pbias,
    float* __restrict__ flags) {
  int b = blockIdx.x;
  int lane = threadIdx.x;
  const float* h = h2 + (size_t)b * (DIM / 2) + lane * 4;
  float4 hv = *(const float4*)h;
  float lg[3];
#pragma unroll
  for (int o = 0; o < 3; ++o) {
    const float* w = w3 + (size_t)o * (DIM / 2) + lane * 4;
    float4 wv = *(const float4*)w;
    float acc = fmaf(hv.x, wv.x, fmaf(hv.y, wv.y, fmaf(hv.z, wv.z, hv.w * wv.w)));
#pragma unroll
    for (int m = 32; m >= 1; m >>= 1) acc += __shfl_xor(acc, m);
    lg[o] = (acc + b3[o] + pbias[o]) * (1.0f / PATT);
  }
  if (lane == 0) {
    float m = fmaxf(lg[0], fmaxf(lg[1], lg[2]));
    float e0 = expf(lg[0] - m), e1 = expf(lg[1] - m), e2 = expf(lg[2] - m);
    float s = e0 + e1 + e2;
    float p0 = e0 / s, p1 = e1 / s, p2 = e2 / s;
    float* f = flags + b * 16;
    f[0] = p0; f[1] = p1; f[2] = p2;
    float cn = (p1 > THRESH) ? 1.f : 0.f;
    float cl = (p0 + p1 > THRESH) ? 1.f : 0.f;
    float cs = (p1 + p2 > THRESH) ? 1.f : 0.f;
    float cls = (p0 + p1 + p2 > THRESH) ? 1.f : 0.f;
    f[3] = cn; f[4] = cl; f[5] = cs; f[6] = cls;
    f[7] = ((cls != cl) || (cs != cn)) ? 1.f : 0.f;   // sparse mask matters
  }
}

// qkv layout: fp32, (B*SEQ) x 1536 row-major; q at +0, k at +512, v at +1024.

// ---------------- banded attention (fast path) ----------------
__global__ __launch_bounds__(256) void attn_banded_kernel(
    const float* __restrict__ flags, const float* __restrict__ qkv,
    __hip_bfloat16* __restrict__ ao) {
  int bid = blockIdx.x;                 // NB*NH*64 blocks, 16 q each
  int qb = bid & 63;
  int h = (bid >> 6) & 7;
  int b = bid >> 9;
  const float* f = flags + b * 16;
  if (f[7] > 0.5f || f[3] > 0.5f) return;
  int t = threadIdx.x;
  int q0 = qb << 4;
  const float* base = qkv + (size_t)b * SEQ * QKVN;
  int ho = h * HDIM;

  if (f[4] < 0.5f) {
    int d = t & 63;
    float val = base[1024 + ho + d];
    for (int qq = t >> 6; qq < 16; qq += 4)
      ao[((size_t)b * SEQ + q0 + qq) * DIM + ho + d] = __float2bfloat16(val);
    return;
  }

  __shared__ float kx[48][65];
  __shared__ float vx[48][64];
  __shared__ float qx[16][64];
  __shared__ float px[16][48];

  int d = t & 63;
  for (int r = t >> 6; r < 48; r += 4) {
    int j = q0 - HALFW + r;
    bool ok = (j >= 0) && (j < SEQ);
    kx[r][d] = ok ? base[(size_t)j * QKVN + 512 + ho + d] : 0.f;
    vx[r][d] = ok ? base[(size_t)j * QKVN + 1024 + ho + d] : 0.f;
  }
  for (int r = t >> 6; r < 16; r += 4)
    qx[r][d] = base[(size_t)(q0 + r) * QKVN + ho + d];
  __syncthreads();

  int w = t >> 6;
  int lane = t & 63;
  for (int qi = 0; qi < 4; ++qi) {
    int qq = w * 4 + qi;
    int q = q0 + qq;
    if (lane < 48) px[qq][lane] = 0.f;
    int j = q - HALFW + lane;
    bool valid = (lane <= 2 * HALFW) && (j >= 0) && (j < SEQ);
    int jb = qq + lane;
    float s = -INFINITY;
    if (valid) {
      float acc = 0.f;
#pragma unroll
      for (int dd = 0; dd < 64; ++dd) acc = fmaf(qx[qq][dd], kx[jb][dd], acc);
      s = acc * SCALE;
    }
    float m = s;
#pragma unroll
    for (int msk = 32; msk >= 1; msk >>= 1) m = fmaxf(m, __shfl_xor(m, msk));
    float p = valid ? expf(s - m) : 0.f;
    float sum = p;
#pragma unroll
    for (int msk = 32; msk >= 1; msk >>= 1) sum += __shfl_xor(sum, msk);
    p = p / sum;
    if (valid) px[qq][jb] = p;
    __syncthreads();
    float o = 0.f;
#pragma unroll 8
    for (int r = 0; r < 48; ++r) o = fmaf(px[qq][r], vx[r][lane], o);
    ao[((size_t)b * SEQ + q) * DIM + ho + lane] = __float2bfloat16(o);
  }
}

// ---------------- generic fallback ----------------
__device__ __forceinline__ int block_sum_i(int v, int* red, int t) {
#pragma unroll
  for (int m = 32; m >= 1; m >>= 1) v += __shfl_xor(v, m);
  __syncthreads();
  if ((t & 63) == 0) red[t >> 6] = v;
  __syncthreads();
  return red[0] + red[1] + red[2] + red[3];
}
__device__ __forceinline__ float block_sum_f(float v, float* red, int t) {
#pragma unroll
  for (int m = 32; m >= 1; m >>= 1) v += __shfl_xor(v, m);
  __syncthreads();
  if ((t & 63) == 0) red[t >> 6] = v;
  __syncthreads();
  return red[0] + red[1] + red[2] + red[3];
}
__device__ __forceinline__ float block_max_f(float v, float* red, int t) {
#pragma unroll
  for (int m = 32; m >= 1; m >>= 1) v = fmaxf(v, __shfl_xor(v, m));
  __syncthreads();
  if ((t & 63) == 0) red[t >> 6] = v;
  __syncthreads();
  return fmaxf(fmaxf(red[0], red[1]), fmaxf(red[2], red[3]));
}

__global__ __launch_bounds__(256) void attn_generic_kernel(
    const float* __restrict__ flags, const float* __restrict__ qkv,
    const float* __restrict__ sw, const float* __restrict__ sb,
    __hip_bfloat16* __restrict__ ao) {
  int bid = blockIdx.x;            // NB*NH*256 blocks, 4 q each
  int qg = bid & 255;
  int h = (bid >> 8) & 7;
  int b = bid >> 11;
  const float* f = flags + b * 16;
  bool need_sparse = f[7] > 0.5f;
  bool cn_b = f[3] > 0.5f;
  if (!(need_sparse || cn_b)) return;

  int t = threadIdx.x;
  const float* base = qkv + (size_t)b * SEQ * QKVN;
  int ho = h * HDIM;
  float c_n = f[3], c_l = f[4], c_s = f[5], c_ls = f[6];
  float swh = sw[h], sbh = sb[h];

  __shared__ float s_sh[SEQ];
  __shared__ float q_sh[HDIM];
  __shared__ unsigned u_sh[SEQ];
  __shared__ int sc_a[SEQ];
  __shared__ int sc_b[SEQ];
  __shared__ float redf[4];
  __shared__ int redi[4];

  for (int qi = 0; qi < 4; ++qi) {
    int q = qg * 4 + qi;
    if (t < HDIM) q_sh[t] = base[(size_t)q * QKVN + ho + t];
    __syncthreads();
    for (int j = t; j < SEQ; j += 256) {
      const float* kr = base + (size_t)j * QKVN + 512 + ho;
      float acc = 0.f;
#pragma unroll
      for (int dd = 0; dd < HDIM; ++dd) acc = fmaf(q_sh[dd], kr[dd], acc);
      s_sh[j] = acc * SCALE;
    }
    __syncthreads();

    if (need_sparse) {
      for (int j = t; j < SEQ; j += 256) {
        unsigned bits = __float_as_uint(fmaf(s_sh[j], swh, sbh));
        u_sh[j] = bits ^ ((bits & 0x80000000u) ? 0xFFFFFFFFu : 0x80000000u);
      }
      __syncthreads();
      unsigned V = 0u;
      for (int bit = 31; bit >= 0; --bit) {
        unsigned cand = V | (1u << bit);
        int c = 0;
        for (int j = t; j < SEQ; j += 256) c += (u_sh[j] >= cand) ? 1 : 0;
        c = block_sum_i(c, redi, t);
        if (c >= KTOP) V = cand;
      }
      int g = 0;
      for (int j = t; j < SEQ; j += 256) g += (u_sh[j] > V) ? 1 : 0;
      g = block_sum_i(g, redi, t);
      int r = KTOP - g;
      for (int j = t; j < SEQ; j += 256) sc_a[j] = (u_sh[j] == V) ? 1 : 0;
      __syncthreads();
      int* src = sc_a; int* dst = sc_b;
      for (int off = 1; off < SEQ; off <<= 1) {
        for (int j = t; j < SEQ; j += 256)
          dst[j] = src[j] + ((j >= off) ? src[j - off] : 0);
        __syncthreads();
        int* tmp = src; src = dst; dst = tmp;
      }
      for (int j = t; j < SEQ; j += 256) {
        bool sp = (u_sh[j] > V) || ((u_sh[j] == V) && (src[j] - 1 < r));
        bool local = (j >= q - HALFW) && (j <= q + HALFW);
        float cv = local ? (sp ? c_ls : c_l) : (sp ? c_s : c_n);
        if (cv < 0.5f) s_sh[j] = -INFINITY;
      }
    } else {
      for (int j = t; j < SEQ; j += 256) {
        bool local = (j >= q - HALFW) && (j <= q + HALFW);
        float cv = local ? c_l : c_n;
        if (cv < 0.5f) s_sh[j] = -INFINITY;
      }
    }
    __syncthreads();

    int anyc = 0;
    for (int j = t; j < SEQ; j += 256) anyc += (s_sh[j] != -INFINITY) ? 1 : 0;
    anyc = block_sum_i(anyc, redi, t);
    if (anyc == 0 && t == 0) s_sh[0] = 0.f;
    __syncthreads();

    float mx = -INFINITY;
    for (int j = t; j < SEQ; j += 256) mx = fmaxf(mx, s_sh[j]);
    mx = block_max_f(mx, redf, t);
    float ls = 0.f;
    for (int j = t; j < SEQ; j += 256) {
      float p = (s_sh[j] == -INFINITY) ? 0.f : expf(s_sh[j] - mx);
      s_sh[j] = p; ls += p;
    }
    ls = block_sum_f(ls, redf, t);
    float inv = 1.f / ls;

    int dd = t & 63, jg = t >> 6;
    float acc = 0.f;
    for (int j = jg; j < SEQ; j += 4)
      acc = fmaf(s_sh[j] * inv, base[(size_t)j * QKVN + 1024 + ho + dd], acc);
    float* redo = (float*)u_sh;
    __syncthreads();
    redo[t] = acc;
    __syncthreads();
    if (t < 64) {
      float o = redo[t] + redo[t + 64] + redo[t + 128] + redo[t + 192];
      ao[((size_t)b * SEQ + q) * DIM + ho + t] = __float2bfloat16(o);
    }
    __syncthreads();
  }
}

extern "C" void kernel_launch(void* const* d_in, const int* in_sizes, int n_in,
                              void* d_out, int out_size, void* d_ws, size_t ws_size,
                              hipStream_t stream) {
  const float* x      = (const float*)d_in[0];
  const float* qkv_w  = (const float*)d_in[1];
  const float* proj_w = (const float*)d_in[2];
  const float* proj_b = (const float*)d_in[3];
  const float* ps_w1  = (const float*)d_in[4];
  const float* ps_b1  = (const float*)d_in[5];
  const float* ps_w2  = (const float*)d_in[6];
  const float* ps_b2  = (const float*)d_in[7];
  const float* ps_w3  = (const float*)d_in[8];
  const float* ps_b3  = (const float*)d_in[9];
  const float* pbias  = (const float*)d_in[10];
  const float* sw     = (const float*)d_in[11];
  const float* sb     = (const float*)d_in[12];
  float* out = (float*)d_out;

  char* w = (char*)d_ws;
  float* flags = (float*)w;              w += 256;
  float* partial = (float*)w;            w += (size_t)NB * 32 * DIM * 4;
  float* pooled = (float*)w;             w += (size_t)NB * DIM * 4;
  float* h1 = (float*)w;                 w += (size_t)NB * DIM * 4;
  float* h2 = (float*)w;                 w += (size_t)NB * (DIM / 2) * 4;
  float* qkv = (float*)w;                w += (size_t)NB * SEQ * QKVN * 4;
  __hip_bfloat16* xb  = (__hip_bfloat16*)w;  w += (size_t)NB * SEQ * DIM * 2;
  __hip_bfloat16* wqb = (__hip_bfloat16*)w;  w += (size_t)QKVN * DIM * 2;
  __hip_bfloat16* wpb = (__hip_bfloat16*)w;  w += (size_t)DIM * DIM * 2;
  __hip_bfloat16* aob = (__hip_bfloat16*)w;  w += (size_t)NB * SEQ * DIM * 2;

  hipLaunchKernelGGL(cvt_all_kernel, dim3(1536), dim3(256), 0, stream,
                     x, qkv_w, proj_w, xb, wqb, wpb);
  hipLaunchKernelGGL(partial_pool_kernel, dim3(NB * 32), dim3(256), 0, stream,
                     x, partial);
  hipLaunchKernelGGL(pool_finish_kernel, dim3(8), dim3(256), 0, stream,
                     partial, pooled);
  hipLaunchKernelGGL(mlp1_kernel, dim3(512), dim3(256), 0, stream,
                     pooled, ps_w1, ps_b1, h1);
  hipLaunchKernelGGL(mlp2_kernel, dim3(256), dim3(256), 0, stream,
                     h1, ps_w2, ps_b2, h2);
  hipLaunchKernelGGL(mlp3_flags_kernel, dim3(NB), dim3(64), 0, stream,
                     h2, ps_w3, ps_b3, pbias, flags);
  hipLaunchKernelGGL(gemm_bt_bf16_kernel, dim3(QKVN / 128, (NB * SEQ) / 128), dim3(256), 0, stream,
                     xb, wqb, (const float*)nullptr, qkv, QKVN, DIM);
  hipLaunchKernelGGL(attn_banded_kernel, dim3(NB * NH * (SEQ / 16)), dim3(256), 0, stream,
                     flags, qkv, aob);
  hipLaunchKernelGGL(attn_generic_kernel, dim3(NB * NH * (SEQ / 4)), dim3(256), 0, stream,
                     flags, qkv, sw, sb, aob);
  hipLaunchKernelGGL(gemm_bt_bf16_kernel, dim3(DIM / 128, (NB * SEQ) / 128), dim3(256), 0, stream,
                     aob, wpb, proj_b, out, DIM, DIM);
}